// Round 3
// baseline (154.386 us; speedup 1.0000x reference)
//
#include <hip/hip_runtime.h>
#include <hip/hip_bf16.h>
#include <cstdint>
#include <cstddef>

// Problem constants
#define BB 8192
#define UU 512
#define KPACK 1024   // D + U
#define NPACK 2048   // 4*U

using frag16 = __attribute__((ext_vector_type(8))) short;   // 8 bf16 = 16 B (4 VGPRs)
using f32x4  = __attribute__((ext_vector_type(4))) float;

__device__ inline float fast_sigmoid(float x) { return 1.0f / (1.0f + __expf(-x)); }
__device__ inline float fast_tanh(float x) {
  x = fminf(fmaxf(x, -15.f), 15.f);
  float e = __expf(-2.0f * x);
  return (1.0f - e) / (1.0f + e);
}

// packed RNE f32x2 -> bf16x2 (v_cvt_pk_bf16_f32 on gfx950 via hip_bf16.h)
__device__ inline unsigned cvt2(float lo, float hi) {
  __hip_bfloat162 b = __float22bfloat162_rn(float2{lo, hi});
  union { __hip_bfloat162 b; unsigned u; } v; v.b = b;
  return v.u;
}

// ---- merged pack kernel (UNCHANGED from verified version) ----
__global__ __launch_bounds__(256) void pack_kernel(const float* __restrict__ x,
                                                   const float* __restrict__ h,
                                                   const float* __restrict__ W,
                                                   const float* __restrict__ R,
                                                   short* __restrict__ Xp,
                                                   short* __restrict__ Bt) {
  if (blockIdx.x < 4096) {
    int idx = blockIdx.x * 256 + threadIdx.x;
    int row = idx >> 7;             // /128 chunks per row
    int k8  = (idx & 127) << 3;     // 0..1016  (wave-uniform x/h split)
    const float* src = (k8 < 512) ? (x + (size_t)row * 512 + k8)
                                  : (h + (size_t)row * 512 + (k8 - 512));
    float4 a = *(const float4*)(src);
    float4 b = *(const float4*)(src + 4);
    uint4 o;
    o.x = cvt2(a.x, a.y);
    o.y = cvt2(a.z, a.w);
    o.z = cvt2(b.x, b.y);
    o.w = cvt2(b.z, b.w);
    *(uint4*)(Xp + ((size_t)idx << 3)) = o;
  } else {
    __shared__ float tile[64][65];   // +1 pad: conflict-free transpose
    int b2 = blockIdx.x - 4096;      // 512 blocks: 32 n-tiles x 16 k-tiles
    int nb = (b2 & 31) * 64;
    int kb = (b2 >> 5) * 64;
    int t  = threadIdx.x;
#pragma unroll
    for (int rep = 0; rep < 16; ++rep) {
      int kr = rep * 4 + (t >> 6);
      int c  = t & 63;
      int kg = kb + kr;
      const float* s = (kg < 512) ? (W + (size_t)kg * 2048) : (R + (size_t)(kg - 512) * 2048);
      tile[c][kr] = s[nb + c];
    }
    __syncthreads();
#pragma unroll
    for (int rep = 0; rep < 4; ++rep) {
      int nn = rep * 16 + (t >> 4);
      int k4 = (t & 15) << 2;
      uint2 o;
      o.x = cvt2(tile[nn][k4 + 0], tile[nn][k4 + 1]);
      o.y = cvt2(tile[nn][k4 + 2], tile[nn][k4 + 3]);
      *(uint2*)(Bt + (size_t)(nb + nn) * 1024 + kb + k4) = o;
    }
  }
}

// ---- fused GEMM + LSTM pointwise: R0 structure + BK=32 double-buffer ----
// Tile 128x128 (32 units x 4 gates), 4 waves (wm=wave&1, wn=wave>>1),
// wave-tile 64x64, acc[4][4]. BK=32, DOUBLE-buffered: LDS = 2 x 16 KB = 32 KB
// -> 4 blocks/CU preserved (R0's TLP). Per K-step:
//   s_barrier            (all waves done reading buf[(t+1)&1] last step)
//   STAGE(t+1)           (4 global_load_lds -> buf[(t+1)&1], fly during compute)
//   s_waitcnt vmcnt(4)   (COUNTED: waits only tile-t loads; t+1 stays in flight)
//   s_barrier            (tile-t landed in all waves)
//   8 ds_read_b128 + 16 MFMA on buf[t&1]
// Never drains vmcnt to 0 in the loop -> the per-step HBM-latency exposure of
// the single-buffered R0 version is gone, TLP unchanged.
// LDS layout (BK=32 rows are 64B): 64 lines x 128B, line L = row>>1, slot
// s = (((row&1)<<2)|chunk) ^ (L&7) -- same XOR-involution class as the
// verified 0-conflict R0 swizzle, applied to BOTH staging source and read.
// K-slice order unchanged (strict ascending, 32/MFMA) -> numerics identical.
__global__ __launch_bounds__(256, 4) void lstm_mfma_kernel(
    const short* __restrict__ A,     // bf16 [8192][1024]
    const short* __restrict__ Bt,    // bf16 [2048][1024], row n = z column
    const float* __restrict__ bias,  // [2048]
    const float* __restrict__ cprev, // [8192][512]
    float* __restrict__ out)         // h, h, c concatenated
{
  // per buffer: A 4096 shorts (64 lines x 128B) then B 4096 shorts; x2 buffers
  __shared__ short lds[2 * 8192];

  const int tid  = threadIdx.x;
  const int lane = tid & 63;
  const int wave = tid >> 6;
  const int wm = wave & 1, wn = wave >> 1;
  const int bm = blockIdx.x;   // 64
  const int bn = blockIdx.y;   // 16

  // ---- staging decomposition (lane -> LDS line/slot -> tile element) ----
  // gload instr g covers lines g*8..g*8+7 (= tile rows g*16..g*16+15).
  // lane l -> line g*8 + (l>>3), slot l&7. Inverse swizzle on the SOURCE:
  const int l8   = lane >> 3;
  const int sl   = lane & 7;
  const int slin = sl ^ l8;        // linear slot
  const int rpar = slin >> 2;      // row parity within line
  const int cch  = slin & 3;       // k-chunk 0..3 (8 shorts each)

  const short* ga0[2];
  const short* gb0[2];
  int la_off[2], lb_off[2];
#pragma unroll
  for (int i = 0; i < 2; ++i) {
    int g    = wave * 2 + i;                 // 0..7
    int rloc = g * 16 + 2 * l8 + rpar;       // tile row 0..127
    ga0[i]    = A + (size_t)(bm * 128 + rloc) * 1024 + cch * 8;
    la_off[i] = g * 512;                     // shorts (g*1024 bytes)
    int u    = bn * 32 + ((rloc >> 6) << 4) + (rloc & 15);
    int gate = (rloc >> 4) & 3;
    gb0[i]    = Bt + (size_t)(gate * 512 + u) * 1024 + cch * 8;
    lb_off[i] = 4096 + g * 512;
  }

  // issue 4 global_load_lds for K-step kt into buffer bi
  auto STAGE = [&](int kt, int bi) {
    const int k0 = kt * 32;
    short* base = &lds[bi * 8192];
#pragma unroll
    for (int i = 0; i < 2; ++i)
      __builtin_amdgcn_global_load_lds(
          (const __attribute__((address_space(1))) void*)(ga0[i] + k0),
          (__attribute__((address_space(3))) void*)(base + la_off[i]), 16, 0, 0);
#pragma unroll
    for (int i = 0; i < 2; ++i)
      __builtin_amdgcn_global_load_lds(
          (const __attribute__((address_space(1))) void*)(gb0[i] + k0),
          (__attribute__((address_space(3))) void*)(base + lb_off[i]), 16, 0, 0);
  };

  // ---- read-side addressing ----
  // frag row r = w*64 + i*16 + c16: L = r>>1, (L&7) = c16>>1 (i*8, w*32 = 0 mod 8)
  // slot s = (((c16&1)<<2)|q) ^ (c16>>1)  -- wave/i invariant
  const int q   = lane >> 4;
  const int c16 = lane & 15;
  const int s_rd  = (((c16 & 1) << 2) | q) ^ (c16 >> 1);
  const int aoff  = wm * 2048 + (c16 >> 1) * 64 + s_rd * 8;          // shorts
  const int boff  = 4096 + wn * 2048 + (c16 >> 1) * 64 + s_rd * 8;   // shorts

  f32x4 acc[4][4];
#pragma unroll
  for (int i = 0; i < 4; ++i)
#pragma unroll
    for (int j = 0; j < 4; ++j)
      acc[i][j] = f32x4{0.f, 0.f, 0.f, 0.f};

  auto COMPUTE = [&](int kt) {
    const short* base = &lds[(kt & 1) * 8192];
    frag16 af[4], bfv[4];
#pragma unroll
    for (int i = 0; i < 4; ++i)
      af[i] = *(const frag16*)(base + aoff + i * 512);
#pragma unroll
    for (int j = 0; j < 4; ++j)
      bfv[j] = *(const frag16*)(base + boff + j * 512);
#pragma unroll
    for (int i = 0; i < 4; ++i)
#pragma unroll
      for (int j = 0; j < 4; ++j)
        acc[i][j] = __builtin_amdgcn_mfma_f32_16x16x32_bf16(af[i], bfv[j], acc[i][j], 0, 0, 0);
  };

  STAGE(0, 0);
  for (int kt = 0; kt < 31; ++kt) {
    __builtin_amdgcn_s_barrier();                      // buf[(kt+1)&1] free to overwrite
    STAGE(kt + 1, (kt + 1) & 1);
    asm volatile("s_waitcnt vmcnt(4)" ::: "memory");   // tile-kt loads landed (kt+1 in flight)
    __builtin_amdgcn_s_barrier();                      // ..in every wave
    COMPUTE(kt);
  }
  asm volatile("s_waitcnt vmcnt(0)" ::: "memory");     // tile-31 loads landed
  __builtin_amdgcn_s_barrier();
  COMPUTE(31);

  // epilogue: lane-local LSTM pointwise. col=lane&15 -> unit, frag col j -> gate.
  const int u = bn * 32 + wn * 16 + c16;
  const float b0 = bias[u];
  const float b1 = bias[512 + u];
  const float b2 = bias[1024 + u];
  const float b3 = bias[1536 + u];
  float* outh0 = out;
  float* outh1 = out + (size_t)BB * UU;
  float* outc  = out + (size_t)2 * BB * UU;

#pragma unroll
  for (int i = 0; i < 4; ++i) {
    int row0 = bm * 128 + wm * 64 + i * 16 + q * 4;
#pragma unroll
    for (int r = 0; r < 4; ++r) {
      size_t off = (size_t)(row0 + r) * UU + u;
      float z0 = acc[i][0][r] + b0;
      float z1 = acc[i][1][r] + b1;
      float z2 = acc[i][2][r] + b2;
      float z3 = acc[i][3][r] + b3;
      float ig = fast_sigmoid(z0);
      float fg = fast_sigmoid(z1);
      float gg = fast_tanh(z2);
      float og = fast_sigmoid(z3);
      float cp = cprev[off];
      float cc = fg * cp + ig * gg;
      float hh = og * fast_tanh(cc);
      outh0[off] = hh;
      outh1[off] = hh;
      outc[off]  = cc;
    }
  }
}

extern "C" void kernel_launch(void* const* d_in, const int* in_sizes, int n_in,
                              void* d_out, int out_size, void* d_ws, size_t ws_size,
                              hipStream_t stream) {
  const float* x  = (const float*)d_in[0];
  const float* h  = (const float*)d_in[1];
  const float* c  = (const float*)d_in[2];
  const float* W  = (const float*)d_in[3];
  const float* R  = (const float*)d_in[4];
  const float* b  = (const float*)d_in[5];
  float* out = (float*)d_out;

  short* Xp = (short*)d_ws;                        // 16 MB bf16 [8192][1024]
  short* Bt = Xp + (size_t)BB * KPACK;             // 4 MB  bf16 [2048][1024]

  pack_kernel<<<4608, 256, 0, stream>>>(x, h, W, R, Xp, Bt);
  lstm_mfma_kernel<<<dim3(64, 16), 256, 0, stream>>>(Xp, Bt, b, c, out);
}

// Round 4
// 151.400 us; speedup vs baseline: 1.0197x; 1.0197x over previous
//
#include <hip/hip_runtime.h>
#include <hip/hip_bf16.h>
#include <cstdint>
#include <cstddef>

// Problem constants
#define BB 8192
#define UU 512
#define KPACK 1024   // D + U
#define NPACK 2048   // 4*U

using frag16 = __attribute__((ext_vector_type(8))) short;   // 8 bf16 = 16 B (4 VGPRs)
using f32x4  = __attribute__((ext_vector_type(4))) float;

__device__ inline float fast_sigmoid(float x) { return 1.0f / (1.0f + __expf(-x)); }
__device__ inline float fast_tanh(float x) {
  x = fminf(fmaxf(x, -15.f), 15.f);
  float e = __expf(-2.0f * x);
  return (1.0f - e) / (1.0f + e);
}

// packed RNE f32x2 -> bf16x2 (v_cvt_pk_bf16_f32 on gfx950 via hip_bf16.h)
__device__ inline unsigned cvt2(float lo, float hi) {
  __hip_bfloat162 b = __float22bfloat162_rn(float2{lo, hi});
  union { __hip_bfloat162 b; unsigned u; } v; v.b = b;
  return v.u;
}

// ---- merged pack kernel (UNCHANGED from verified version) ----
__global__ __launch_bounds__(256) void pack_kernel(const float* __restrict__ x,
                                                   const float* __restrict__ h,
                                                   const float* __restrict__ W,
                                                   const float* __restrict__ R,
                                                   short* __restrict__ Xp,
                                                   short* __restrict__ Bt) {
  if (blockIdx.x < 4096) {
    int idx = blockIdx.x * 256 + threadIdx.x;
    int row = idx >> 7;             // /128 chunks per row
    int k8  = (idx & 127) << 3;     // 0..1016  (wave-uniform x/h split)
    const float* src = (k8 < 512) ? (x + (size_t)row * 512 + k8)
                                  : (h + (size_t)row * 512 + (k8 - 512));
    float4 a = *(const float4*)(src);
    float4 b = *(const float4*)(src + 4);
    uint4 o;
    o.x = cvt2(a.x, a.y);
    o.y = cvt2(a.z, a.w);
    o.z = cvt2(b.x, b.y);
    o.w = cvt2(b.z, b.w);
    *(uint4*)(Xp + ((size_t)idx << 3)) = o;
  } else {
    __shared__ float tile[64][65];   // +1 pad: conflict-free transpose
    int b2 = blockIdx.x - 4096;      // 512 blocks: 32 n-tiles x 16 k-tiles
    int nb = (b2 & 31) * 64;
    int kb = (b2 >> 5) * 64;
    int t  = threadIdx.x;
#pragma unroll
    for (int rep = 0; rep < 16; ++rep) {
      int kr = rep * 4 + (t >> 6);
      int c  = t & 63;
      int kg = kb + kr;
      const float* s = (kg < 512) ? (W + (size_t)kg * 2048) : (R + (size_t)(kg - 512) * 2048);
      tile[c][kr] = s[nb + c];
    }
    __syncthreads();
#pragma unroll
    for (int rep = 0; rep < 4; ++rep) {
      int nn = rep * 16 + (t >> 4);
      int k4 = (t & 15) << 2;
      uint2 o;
      o.x = cvt2(tile[nn][k4 + 0], tile[nn][k4 + 1]);
      o.y = cvt2(tile[nn][k4 + 2], tile[nn][k4 + 3]);
      *(uint2*)(Bt + (size_t)(nb + nn) * 1024 + kb + k4) = o;
    }
  }
}

// ---- fused GEMM + LSTM pointwise: R0 structure, 8 waves per block ----
// Identical tile (128x128 = 32 units x 4 gates), identical BK=64 single-
// buffered stage->sync->compute->sync loop, identical XOR chunk swizzle and
// gate-interleaved B gather (all harness-verified in the 50.4us version).
// ONLY change: 512 threads = 8 waves (wm=wave&3 row band of 32, wn=wave>>2
// col half of 64), wave-tile 32x64, acc[2][4] (32 regs). Combined reg
// footprint ~75 (vs 128) -> ~6-7 waves/SIMD -> 3 blocks x 8 waves = 24
// waves/CU (was 16): +50% wave-level TLP to hide the per-step stage drain,
// finer MFMA clusters (16 per wave-step), 4 gloads/wave (was 8).
// Per-output k-accumulation order unchanged -> numerics identical.
__global__ __launch_bounds__(512, 6) void lstm_mfma_kernel(
    const short* __restrict__ A,     // bf16 [8192][1024]
    const short* __restrict__ Bt,    // bf16 [2048][1024], row n = z column
    const float* __restrict__ bias,  // [2048]
    const float* __restrict__ cprev, // [8192][512]
    float* __restrict__ out)         // h, h, c concatenated
{
  __shared__ short lds_a[128 * 64];
  __shared__ short lds_b[128 * 64];

  const int tid  = threadIdx.x;
  const int lane = tid & 63;
  const int wave = tid >> 6;     // 0..7
  const int wm = wave & 3;       // row band: rows wm*32 .. +31
  const int wn = wave >> 2;      // col half: cols wn*64 .. +63 (16u x 4 gates)
  const int bm = blockIdx.x;     // 64
  const int bn = blockIdx.y;     // 16

  // staging decomposition: 8 lanes per 128B row, xor-swizzle k-chunks
  // (identical involution to verified version: LDS slot sl holds global
  //  chunk sl ^ (row&7); read side applies the same XOR).
  const int r8  = lane >> 3;
  const int kg  = lane & 7;
  const int kgx = kg ^ r8;

  const short* ga[2];
  const short* gb[2];
  int ls_off[2];
#pragma unroll
  for (int i = 0; i < 2; ++i) {
    int g    = wave * 2 + i;             // 0..15 groups of 8 rows
    int rowl = g * 8 + r8;               // local row 0..127
    ga[i] = A + (size_t)(bm * 128 + rowl) * 1024 + kgx * 8;
    int u    = bn * 32 + ((rowl >> 6) << 4) + (rowl & 15);
    int gate = (rowl >> 4) & 3;
    gb[i] = Bt + (size_t)(gate * 512 + u) * 1024 + kgx * 8;
    ls_off[i] = g * 512;                 // shorts: g*1024 bytes
  }

  const int q   = lane >> 4;
  const int c16 = lane & 15;
  const int mx  = c16 & 7;

  f32x4 acc[2][4];
#pragma unroll
  for (int i = 0; i < 2; ++i)
#pragma unroll
    for (int j = 0; j < 4; ++j)
      acc[i][j] = f32x4{0.f, 0.f, 0.f, 0.f};

  for (int kt = 0; kt < 16; ++kt) {
    const int k0 = kt * 64;
#pragma unroll
    for (int i = 0; i < 2; ++i)
      __builtin_amdgcn_global_load_lds(
          (const __attribute__((address_space(1))) void*)(ga[i] + k0),
          (__attribute__((address_space(3))) void*)(lds_a + ls_off[i]), 16, 0, 0);
#pragma unroll
    for (int i = 0; i < 2; ++i)
      __builtin_amdgcn_global_load_lds(
          (const __attribute__((address_space(1))) void*)(gb[i] + k0),
          (__attribute__((address_space(3))) void*)(lds_b + ls_off[i]), 16, 0, 0);
    __syncthreads();   // compiler emits vmcnt(0) drain here
#pragma unroll
    for (int s = 0; s < 2; ++s) {
      const int kch = (((s << 2) + q) ^ mx) << 3;
      frag16 af[2], bfv[4];
#pragma unroll
      for (int i = 0; i < 2; ++i)
        af[i] = *(const frag16*)(lds_a + (wm * 32 + i * 16 + c16) * 64 + kch);
#pragma unroll
      for (int j = 0; j < 4; ++j)
        bfv[j] = *(const frag16*)(lds_b + (wn * 64 + j * 16 + c16) * 64 + kch);
#pragma unroll
      for (int i = 0; i < 2; ++i)
#pragma unroll
        for (int j = 0; j < 4; ++j)
          acc[i][j] = __builtin_amdgcn_mfma_f32_16x16x32_bf16(af[i], bfv[j], acc[i][j], 0, 0, 0);
    }
    __syncthreads();
  }

  // epilogue: lane-local LSTM pointwise. col = wn*64 + j*16 + c16 -> gate j,
  // unit = bn*32 + wn*16 + c16 (same verified formula).
  const int u = bn * 32 + wn * 16 + c16;
  const float b0 = bias[u];
  const float b1 = bias[512 + u];
  const float b2 = bias[1024 + u];
  const float b3 = bias[1536 + u];
  float* outh0 = out;
  float* outh1 = out + (size_t)BB * UU;
  float* outc  = out + (size_t)2 * BB * UU;

#pragma unroll
  for (int i = 0; i < 2; ++i) {
    int row0 = bm * 128 + wm * 32 + i * 16 + q * 4;
#pragma unroll
    for (int r = 0; r < 4; ++r) {
      size_t off = (size_t)(row0 + r) * UU + u;
      float z0 = acc[i][0][r] + b0;
      float z1 = acc[i][1][r] + b1;
      float z2 = acc[i][2][r] + b2;
      float z3 = acc[i][3][r] + b3;
      float ig = fast_sigmoid(z0);
      float fg = fast_sigmoid(z1);
      float gg = fast_tanh(z2);
      float og = fast_sigmoid(z3);
      float cp = cprev[off];
      float cc = fg * cp + ig * gg;
      float hh = og * fast_tanh(cc);
      outh0[off] = hh;
      outh1[off] = hh;
      outc[off]  = cc;
    }
  }
}

extern "C" void kernel_launch(void* const* d_in, const int* in_sizes, int n_in,
                              void* d_out, int out_size, void* d_ws, size_t ws_size,
                              hipStream_t stream) {
  const float* x  = (const float*)d_in[0];
  const float* h  = (const float*)d_in[1];
  const float* c  = (const float*)d_in[2];
  const float* W  = (const float*)d_in[3];
  const float* R  = (const float*)d_in[4];
  const float* b  = (const float*)d_in[5];
  float* out = (float*)d_out;

  short* Xp = (short*)d_ws;                        // 16 MB bf16 [8192][1024]
  short* Bt = Xp + (size_t)BB * KPACK;             // 4 MB  bf16 [2048][1024]

  pack_kernel<<<4608, 256, 0, stream>>>(x, h, W, R, Xp, Bt);
  lstm_mfma_kernel<<<dim3(64, 16), 512, 0, stream>>>(Xp, Bt, b, c, out);
}

// Round 5
// 145.451 us; speedup vs baseline: 1.0614x; 1.0409x over previous
//
#include <hip/hip_runtime.h>
#include <hip/hip_bf16.h>
#include <cstdint>
#include <cstddef>

// Problem constants
#define BB 8192
#define UU 512
#define KPACK 1024   // D + U
#define NPACK 2048   // 4*U

using frag16 = __attribute__((ext_vector_type(8))) short;   // 8 bf16 = 16 B (4 VGPRs)
using f32x4  = __attribute__((ext_vector_type(4))) float;

// Epilogue transcendentals: single-instruction v_rcp_f32 instead of the IEEE
// div sequence (~6-8 VALU each; no -ffast-math). sigma(x) = rcp(1+e^-x).
// tanh(x) = 2*rcp(1+e^-2x) - 1  ==  (1-e)/(1+e)  (same function, inf-safe:
// e->inf => rcp(inf)=0 => -1; e->0 => 1). rcp err ~1 ulp, invisible at
// bf16-scale absmax.
__device__ inline float fast_sigmoid(float x) {
  float e = __expf(-x);
  return __builtin_amdgcn_rcpf(1.0f + e);
}
__device__ inline float fast_tanh(float x) {
  float e = __expf(-2.0f * x);
  return fmaf(2.0f, __builtin_amdgcn_rcpf(1.0f + e), -1.0f);
}

// packed RNE f32x2 -> bf16x2 (v_cvt_pk_bf16_f32 on gfx950 via hip_bf16.h)
__device__ inline unsigned cvt2(float lo, float hi) {
  __hip_bfloat162 b = __float22bfloat162_rn(float2{lo, hi});
  union { __hip_bfloat162 b; unsigned u; } v; v.b = b;
  return v.u;
}

// ---- merged pack kernel (UNCHANGED from verified version) ----
__global__ __launch_bounds__(256) void pack_kernel(const float* __restrict__ x,
                                                   const float* __restrict__ h,
                                                   const float* __restrict__ W,
                                                   const float* __restrict__ R,
                                                   short* __restrict__ Xp,
                                                   short* __restrict__ Bt) {
  if (blockIdx.x < 4096) {
    int idx = blockIdx.x * 256 + threadIdx.x;
    int row = idx >> 7;             // /128 chunks per row
    int k8  = (idx & 127) << 3;     // 0..1016  (wave-uniform x/h split)
    const float* src = (k8 < 512) ? (x + (size_t)row * 512 + k8)
                                  : (h + (size_t)row * 512 + (k8 - 512));
    float4 a = *(const float4*)(src);
    float4 b = *(const float4*)(src + 4);
    uint4 o;
    o.x = cvt2(a.x, a.y);
    o.y = cvt2(a.z, a.w);
    o.z = cvt2(b.x, b.y);
    o.w = cvt2(b.z, b.w);
    *(uint4*)(Xp + ((size_t)idx << 3)) = o;
  } else {
    __shared__ float tile[64][65];   // +1 pad: conflict-free transpose
    int b2 = blockIdx.x - 4096;      // 512 blocks: 32 n-tiles x 16 k-tiles
    int nb = (b2 & 31) * 64;
    int kb = (b2 >> 5) * 64;
    int t  = threadIdx.x;
#pragma unroll
    for (int rep = 0; rep < 16; ++rep) {
      int kr = rep * 4 + (t >> 6);
      int c  = t & 63;
      int kg = kb + kr;
      const float* s = (kg < 512) ? (W + (size_t)kg * 2048) : (R + (size_t)(kg - 512) * 2048);
      tile[c][kr] = s[nb + c];
    }
    __syncthreads();
#pragma unroll
    for (int rep = 0; rep < 4; ++rep) {
      int nn = rep * 16 + (t >> 4);
      int k4 = (t & 15) << 2;
      uint2 o;
      o.x = cvt2(tile[nn][k4 + 0], tile[nn][k4 + 1]);
      o.y = cvt2(tile[nn][k4 + 2], tile[nn][k4 + 3]);
      *(uint2*)(Bt + (size_t)(nb + nn) * 1024 + kb + k4) = o;
    }
  }
}

// ---- fused GEMM + LSTM pointwise (R0 config: best measured 50.4 us) ----
// Tile: BM=128 (batch) x 32 units x 4 gates (=128 N cols). 4 waves: wm = wave&1
// (rows), wn = wave>>1 (16-unit group). Wave fragment-column j == gate j, so all
// 4 gates of unit u sit in the same lane -> pointwise epilogue is lane-local.
// 32 KB LDS + 64 VGPR -> 4 blocks/CU. GEMM K-loop byte-identical to the
// verified 50.4us version (R1-R4 all showed schedule restructures regress).
// This round's ONLY change: epilogue divisions -> v_rcp_f32 (see above).
__global__ __launch_bounds__(256, 4) void lstm_mfma_kernel(
    const short* __restrict__ A,     // bf16 [8192][1024]
    const short* __restrict__ Bt,    // bf16 [2048][1024], row n = z column
    const float* __restrict__ bias,  // [2048]
    const float* __restrict__ cprev, // [8192][512]
    float* __restrict__ out)         // h, h, c concatenated
{
  __shared__ short lds_a[128 * 64];
  __shared__ short lds_b[128 * 64];

  const int tid  = threadIdx.x;
  const int lane = tid & 63;
  const int wave = tid >> 6;
  const int wm = wave & 1, wn = wave >> 1;
  const int bm = blockIdx.x;   // 64
  const int bn = blockIdx.y;   // 16

  // staging decomposition: 8 lanes per 128B row, xor-swizzle k-chunks.
  const int r8  = lane >> 3;
  const int kg  = lane & 7;
  const int kgx = kg ^ r8;

  const short* ga[4];
  const short* gb[4];
  int ls_off[4];
#pragma unroll
  for (int t = 0; t < 4; ++t) {
    int rowl = wave * 32 + t * 8 + r8;   // local row 0..127
    ga[t] = A + (size_t)(bm * 128 + rowl) * 1024 + kgx * 8;
    int u    = bn * 32 + ((rowl >> 6) << 4) + (rowl & 15);
    int gate = (rowl >> 4) & 3;
    gb[t] = Bt + (size_t)(gate * 512 + u) * 1024 + kgx * 8;
    ls_off[t] = (wave * 32 + t * 8) * 64;
  }

  const int q   = lane >> 4;
  const int c16 = lane & 15;
  const int mx  = c16 & 7;

  f32x4 acc[4][4];
#pragma unroll
  for (int i = 0; i < 4; ++i)
#pragma unroll
    for (int j = 0; j < 4; ++j)
      acc[i][j] = f32x4{0.f, 0.f, 0.f, 0.f};

  for (int kt = 0; kt < 16; ++kt) {
    const int k0 = kt * 64;
#pragma unroll
    for (int t = 0; t < 4; ++t)
      __builtin_amdgcn_global_load_lds(
          (const __attribute__((address_space(1))) void*)(ga[t] + k0),
          (__attribute__((address_space(3))) void*)(lds_a + ls_off[t]), 16, 0, 0);
#pragma unroll
    for (int t = 0; t < 4; ++t)
      __builtin_amdgcn_global_load_lds(
          (const __attribute__((address_space(1))) void*)(gb[t] + k0),
          (__attribute__((address_space(3))) void*)(lds_b + ls_off[t]), 16, 0, 0);
    __syncthreads();   // compiler emits vmcnt(0) drain here
#pragma unroll
    for (int s = 0; s < 2; ++s) {
      const int kch = (((s << 2) + q) ^ mx) << 3;
      frag16 af[4], bf[4];
#pragma unroll
      for (int i = 0; i < 4; ++i)
        af[i] = *(const frag16*)(lds_a + (wm * 64 + i * 16 + c16) * 64 + kch);
#pragma unroll
      for (int j = 0; j < 4; ++j)
        bf[j] = *(const frag16*)(lds_b + (wn * 64 + j * 16 + c16) * 64 + kch);
#pragma unroll
      for (int i = 0; i < 4; ++i)
#pragma unroll
        for (int j = 0; j < 4; ++j)
          acc[i][j] = __builtin_amdgcn_mfma_f32_16x16x32_bf16(af[i], bf[j], acc[i][j], 0, 0, 0);
    }
    __syncthreads();
  }

  // epilogue: lane-local LSTM pointwise. col=lane&15 -> unit, frag col j -> gate.
  const int u = bn * 32 + wn * 16 + c16;
  const float b0 = bias[u];
  const float b1 = bias[512 + u];
  const float b2 = bias[1024 + u];
  const float b3 = bias[1536 + u];
  float* outh0 = out;
  float* outh1 = out + (size_t)BB * UU;
  float* outc  = out + (size_t)2 * BB * UU;

#pragma unroll
  for (int i = 0; i < 4; ++i) {
    int row0 = bm * 128 + wm * 64 + i * 16 + q * 4;
#pragma unroll
    for (int r = 0; r < 4; ++r) {
      size_t off = (size_t)(row0 + r) * UU + u;
      float z0 = acc[i][0][r] + b0;
      float z1 = acc[i][1][r] + b1;
      float z2 = acc[i][2][r] + b2;
      float z3 = acc[i][3][r] + b3;
      float ig = fast_sigmoid(z0);
      float fg = fast_sigmoid(z1);
      float gg = fast_tanh(z2);
      float og = fast_sigmoid(z3);
      float cp = cprev[off];
      float cc = fg * cp + ig * gg;
      float hh = og * fast_tanh(cc);
      outh0[off] = hh;
      outh1[off] = hh;
      outc[off]  = cc;
    }
  }
}

extern "C" void kernel_launch(void* const* d_in, const int* in_sizes, int n_in,
                              void* d_out, int out_size, void* d_ws, size_t ws_size,
                              hipStream_t stream) {
  const float* x  = (const float*)d_in[0];
  const float* h  = (const float*)d_in[1];
  const float* c  = (const float*)d_in[2];
  const float* W  = (const float*)d_in[3];
  const float* R  = (const float*)d_in[4];
  const float* b  = (const float*)d_in[5];
  float* out = (float*)d_out;

  short* Xp = (short*)d_ws;                        // 16 MB bf16 [8192][1024]
  short* Bt = Xp + (size_t)BB * KPACK;             // 4 MB  bf16 [2048][1024]

  pack_kernel<<<4608, 256, 0, stream>>>(x, h, W, R, Xp, Bt);
  lstm_mfma_kernel<<<dim3(64, 16), 256, 0, stream>>>(Xp, Bt, b, c, out);
}